// Round 2
// baseline (618.948 us; speedup 1.0000x reference)
//
#include <hip/hip_runtime.h>
#include <hip/hip_bf16.h>

#define D_MODEL 1024
#define F_DIM   2048
#define NE      8
#define NTOK    8192
#define MAXT    72

typedef __attribute__((ext_vector_type(8))) short bf16x8;
typedef __attribute__((ext_vector_type(4))) float f32x4;

__device__ __forceinline__ unsigned short f2b(float f) {
    unsigned int u = __float_as_uint(f);
    u += 0x7FFFu + ((u >> 16) & 1u);          // RNE
    return (unsigned short)(u >> 16);
}
__device__ __forceinline__ unsigned int pack2(float a, float b) {
    return (unsigned int)f2b(a) | ((unsigned int)f2b(b) << 16);
}
__device__ __forceinline__ void async16(const void* g, void* l) {
    __builtin_amdgcn_global_load_lds((const __attribute__((address_space(1))) void*)g,
                                     (__attribute__((address_space(3))) void*)l, 16, 0, 0);
}

// ------------- ternary quantization: fp32 rows -> bf16 {-s,0,+s} ----------------
template <int K>
__global__ __launch_bounds__(256) void quant_rows(const float* __restrict__ W,
                                                  unsigned short* __restrict__ Q) {
    constexpr int PER = K / 256;   // floats per thread (4 or 8)
    constexpr int PV  = PER / 4;   // float4s per thread
    __shared__ float sred[4];
    const int tid = threadIdx.x;
    const size_t row = blockIdx.x;
    const float4* Wv = (const float4*)(W + row * (size_t)K) + tid * PV;
    float4 v[PV];
#pragma unroll
    for (int i = 0; i < PV; i++) v[i] = Wv[i];
    float s = 0.f;
#pragma unroll
    for (int i = 0; i < PV; i++)
        s += fabsf(v[i].x) + fabsf(v[i].y) + fabsf(v[i].z) + fabsf(v[i].w);
#pragma unroll
    for (int o = 32; o > 0; o >>= 1) s += __shfl_down(s, o);
    if ((tid & 63) == 0) sred[tid >> 6] = s;
    __syncthreads();
    float scale = (sred[0] + sred[1] + sred[2] + sred[3]) * (1.0f / K);
    scale = fmaxf(scale, 1e-5f);
    const float inv = 1.0f / scale;
    unsigned int* Qu = (unsigned int*)(Q + row * (size_t)K) + tid * (PER / 2);
#pragma unroll
    for (int i = 0; i < PV; i++) {
        float q0 = fminf(1.f, fmaxf(-1.f, rintf(v[i].x * inv))) * scale;
        float q1 = fminf(1.f, fmaxf(-1.f, rintf(v[i].y * inv))) * scale;
        float q2 = fminf(1.f, fmaxf(-1.f, rintf(v[i].z * inv))) * scale;
        float q3 = fminf(1.f, fmaxf(-1.f, rintf(v[i].w * inv))) * scale;
        Qu[2 * i]     = pack2(q0, q1);
        Qu[2 * i + 1] = pack2(q2, q3);
    }
}

// ---------------- fused LayerNorm + router (top-1) ------------------------------
__global__ __launch_bounds__(256) void ln_router(const float* __restrict__ x,
                                                 const float* __restrict__ gamma,
                                                 const float* __restrict__ beta,
                                                 const float* __restrict__ rw,
                                                 unsigned short* __restrict__ h,
                                                 int* __restrict__ top_idx,
                                                 float* __restrict__ top_prob,
                                                 int* __restrict__ counts) {
    const int tid = threadIdx.x;
    const size_t tok = blockIdx.x;
    __shared__ float sred[8];
    __shared__ float smr[4 * NE];
    __shared__ float sml[NE];

    const float4 xv = ((const float4*)(x + tok * D_MODEL))[tid];
    float s = xv.x + xv.y + xv.z + xv.w;
    float q = xv.x * xv.x + xv.y * xv.y + xv.z * xv.z + xv.w * xv.w;
#pragma unroll
    for (int o = 32; o > 0; o >>= 1) { s += __shfl_down(s, o); q += __shfl_down(q, o); }
    if ((tid & 63) == 0) { sred[tid >> 6] = s; sred[4 + (tid >> 6)] = q; }
    __syncthreads();
    const float mean = (sred[0] + sred[1] + sred[2] + sred[3]) * (1.0f / D_MODEL);
    const float ex2  = (sred[4] + sred[5] + sred[6] + sred[7]) * (1.0f / D_MODEL);
    const float rstd = rsqrtf(ex2 - mean * mean + 1e-5f);

    const float4 g  = ((const float4*)gamma)[tid];
    const float4 bt = ((const float4*)beta)[tid];
    float hv[4];
    hv[0] = (xv.x - mean) * rstd * g.x + bt.x;
    hv[1] = (xv.y - mean) * rstd * g.y + bt.y;
    hv[2] = (xv.z - mean) * rstd * g.z + bt.z;
    hv[3] = (xv.w - mean) * rstd * g.w + bt.w;
    unsigned int* hr = (unsigned int*)(h + tok * D_MODEL) + tid * 2;
    hr[0] = pack2(hv[0], hv[1]);
    hr[1] = pack2(hv[2], hv[3]);

    float acc[NE];
#pragma unroll
    for (int e = 0; e < NE; e++) {
        const float4 r = ((const float4*)(rw + e * D_MODEL))[tid];
        acc[e] = hv[0] * r.x + hv[1] * r.y + hv[2] * r.z + hv[3] * r.w;
    }
#pragma unroll
    for (int e = 0; e < NE; e++) {
        float t = acc[e];
#pragma unroll
        for (int o = 32; o > 0; o >>= 1) t += __shfl_down(t, o);
        if ((tid & 63) == 0) smr[(tid >> 6) * NE + e] = t;
    }
    __syncthreads();
    if (tid < NE) sml[tid] = smr[tid] + smr[NE + tid] + smr[2 * NE + tid] + smr[3 * NE + tid];
    __syncthreads();
    if (tid == 0) {
        float m = sml[0]; int bi = 0;
#pragma unroll
        for (int e = 1; e < NE; e++) { if (sml[e] > m) { m = sml[e]; bi = e; } }
        float se = 0.f;
#pragma unroll
        for (int e = 0; e < NE; e++) se += __expf(sml[e] - m);
        top_idx[tok]  = bi;
        top_prob[tok] = 1.0f / se;
        atomicAdd(&counts[bi], 1);
    }
}

// ---------------- small bookkeeping kernels -------------------------------------
__global__ void zero_counts(int* counts) { if (threadIdx.x < NE) counts[threadIdx.x] = 0; }

__global__ void scan_tiles(const int* __restrict__ counts, int* __restrict__ offsets,
                           int* __restrict__ cursors, int4* __restrict__ tilemap) {
    if (threadIdx.x != 0) return;
    int off = 0, slot = 0;
    for (int e = 0; e < NE; e++) {
        offsets[e] = off;
        cursors[e] = off;
        int c = counts[e];
        for (int k = 0; k < c; k += 128) {
            int4 t; t.x = e; t.y = off + k; t.z = min(128, c - k); t.w = 0;
            tilemap[slot++] = t;
        }
        off += c;
    }
    offsets[NE] = off;
    for (; slot < MAXT; slot++) { int4 t; t.x = 0; t.y = 0; t.z = 0; t.w = 0; tilemap[slot] = t; }
}

__global__ __launch_bounds__(256) void scatter_tokens(const int* __restrict__ top_idx,
                                                      const float* __restrict__ top_prob,
                                                      int* __restrict__ cursors,
                                                      int* __restrict__ tok_perm,
                                                      float* __restrict__ probg) {
    const int t = blockIdx.x * 256 + threadIdx.x;
    const int e = top_idx[t];
    const int pos = atomicAdd(&cursors[e], 1);
    tok_perm[pos] = t;
    probg[pos] = top_prob[t];
}

__global__ __launch_bounds__(128) void gather_h(const unsigned short* __restrict__ h,
                                                const int* __restrict__ tok_perm,
                                                unsigned short* __restrict__ hg) {
    const int r = blockIdx.x;
    const int src = tok_perm[r];
    const uint4* s = (const uint4*)(h + (size_t)src * D_MODEL);
    uint4* d = (uint4*)(hg + (size_t)r * D_MODEL);
    d[threadIdx.x] = s[threadIdx.x];
}

// ---------------- m97-style bf16 NT GEMM: C[M,N] = A[M,K] * B[N,K]^T ------------
// A,B are bf16; C is fp32.
// EPI: 0 = silu->store bf16 (shared GEMM1), 1 = plain store fp32 (shared GEMM2),
//      2 = tiled silu->store bf16 (routed GEMM1), 3 = tiled scatter-add fp32 (routed GEMM2)
template <int EPI>
__global__ __launch_bounds__(256) void gemm_nt(const unsigned short* __restrict__ A,
                                               const unsigned short* __restrict__ Bw,
                                               void* __restrict__ Cv,
                                               int N, int K,
                                               const int4* __restrict__ tilemap,
                                               long long bstride,
                                               const int* __restrict__ tok_perm,
                                               const float* __restrict__ probg) {
    int m0, rowsValid;
    const unsigned short* B = Bw;
    if (EPI >= 2) {
        int4 tm = tilemap[blockIdx.y];
        rowsValid = tm.z;
        if (rowsValid == 0) return;
        m0 = tm.y;
        B += (size_t)tm.x * (size_t)bstride;
    } else {
        m0 = blockIdx.y * 128;
        rowsValid = 128;
    }
    const int n0 = blockIdx.x * 128;

    __shared__ unsigned short As[128 * 32];
    __shared__ unsigned short Bs[128 * 32];

    const int tid = threadIdx.x;
    const int lane = tid & 63;
    const int w = tid >> 6;
    const int wm = w >> 1, wn = w & 1;

    f32x4 acc[4][4];
#pragma unroll
    for (int i = 0; i < 4; i++)
#pragma unroll
        for (int j = 0; j < 4; j++) acc[i][j] = (f32x4){0.f, 0.f, 0.f, 0.f};

    // staging: LDS tile [row][32] row-major; lane l writes bytes l*16 of its wave's chunk
    const int rS = w * 16 + (lane >> 2);
    const int cS = (lane & 3) * 8;
    const unsigned short* a0 = A + (size_t)(m0 + rS) * K + cS;
    const unsigned short* a1 = A + (size_t)(m0 + rS + 64) * K + cS;
    const unsigned short* b0 = B + (size_t)(n0 + rS) * K + cS;
    const unsigned short* b1 = B + (size_t)(n0 + rS + 64) * K + cS;
    unsigned short* asl = As + w * 512;
    unsigned short* bsl = Bs + w * 512;

    const int fr = lane & 15, fq = lane >> 4;
    const bf16x8* Ar = (const bf16x8*)As;
    const bf16x8* Br = (const bf16x8*)Bs;
    const int aBase = (wm * 64 + fr) * 4 + fq;
    const int bBase = (wn * 64 + fr) * 4 + fq;

    for (int k0 = 0; k0 < K; k0 += 32) {
        async16(a0 + k0, asl);
        async16(a1 + k0, asl + 2048);
        async16(b0 + k0, bsl);
        async16(b1 + k0, bsl + 2048);
        __syncthreads();
        bf16x8 af[4], bfr[4];
#pragma unroll
        for (int i = 0; i < 4; i++) af[i] = Ar[aBase + i * 64];
#pragma unroll
        for (int j = 0; j < 4; j++) bfr[j] = Br[bBase + j * 64];
#pragma unroll
        for (int i = 0; i < 4; i++)
#pragma unroll
            for (int j = 0; j < 4; j++)
                acc[i][j] = __builtin_amdgcn_mfma_f32_16x16x32_bf16(af[i], bfr[j], acc[i][j], 0, 0, 0);
        __syncthreads();
    }

    // epilogue: C/D layout col=lane&15, row=quad*4+reg (m89-verified)
#pragma unroll
    for (int i = 0; i < 4; i++) {
        const int rb = wm * 64 + i * 16 + fq * 4;
#pragma unroll
        for (int t = 0; t < 4; t++) {
            const int r = rb + t;
            if (r < rowsValid) {
#pragma unroll
                for (int j = 0; j < 4; j++) {
                    const int c = n0 + wn * 64 + j * 16 + fr;
                    float v = acc[i][j][t];
                    if (EPI == 0 || EPI == 2) {            // silu -> bf16 intermediate
                        v = v / (1.0f + __expf(-v));
                        ((unsigned short*)Cv)[(size_t)(m0 + r) * N + c] = f2b(v);
                    } else if (EPI == 1) {                 // fp32 store
                        ((float*)Cv)[(size_t)(m0 + r) * N + c] = v;
                    } else {                               // fp32 scatter-add
                        const int tokr = tok_perm[m0 + r];
                        const float p = probg[m0 + r];
                        float* crow = (float*)Cv + (size_t)tokr * N;
                        crow[c] = crow[c] + p * v;
                    }
                }
            }
        }
    }
}

// ---------------- launch ---------------------------------------------------------
extern "C" void kernel_launch(void* const* d_in, const int* in_sizes, int n_in,
                              void* d_out, int out_size, void* d_ws, size_t ws_size,
                              hipStream_t stream) {
    const float* x   = (const float*)d_in[0];
    const float* sw1 = (const float*)d_in[1];
    const float* sw2 = (const float*)d_in[2];
    const float* ew1 = (const float*)d_in[3];
    const float* ew2 = (const float*)d_in[4];
    const float* rw  = (const float*)d_in[5];
    const float* gam = (const float*)d_in[6];
    const float* bet = (const float*)d_in[7];
    float* out = (float*)d_out;

    char* ws = (char*)d_ws;
    const size_t H_OFF    = 0;                                           // h bf16
    const size_t SW1Q_OFF = H_OFF + (size_t)NTOK * D_MODEL * 2;          // 16.78 MB
    const size_t SW2Q_OFF = SW1Q_OFF + (size_t)F_DIM * D_MODEL * 2;      // +4.19 MB
    const size_t EW1Q_OFF = SW2Q_OFF + (size_t)D_MODEL * F_DIM * 2;      // +4.19 MB
    const size_t EW2Q_OFF = EW1Q_OFF + (size_t)NE * F_DIM * D_MODEL * 2; // +33.55 MB
    const size_t H1_OFF   = EW2Q_OFF + (size_t)NE * D_MODEL * F_DIM * 2; // +33.55 MB
    const size_t HG_OFF   = H1_OFF + (size_t)(NTOK + 128) * F_DIM * 2;   // +34.08 MB
    const size_t PERM_OFF = HG_OFF + (size_t)(NTOK + 128) * D_MODEL * 2; // +17.04 MB
    const size_t PROBG_OFF = PERM_OFF + NTOK * 4;
    const size_t IDX_OFF   = PROBG_OFF + NTOK * 4;
    const size_t PROB_OFF  = IDX_OFF + NTOK * 4;
    const size_t CNT_OFF   = PROB_OFF + NTOK * 4;
    const size_t OFFS_OFF  = CNT_OFF + 128;
    const size_t CUR_OFF   = OFFS_OFF + 128;
    const size_t TILE_OFF  = CUR_OFF + 128;

    unsigned short* h     = (unsigned short*)(ws + H_OFF);
    unsigned short* sw1q  = (unsigned short*)(ws + SW1Q_OFF);
    unsigned short* sw2q  = (unsigned short*)(ws + SW2Q_OFF);
    unsigned short* ew1q  = (unsigned short*)(ws + EW1Q_OFF);
    unsigned short* ew2q  = (unsigned short*)(ws + EW2Q_OFF);
    unsigned short* h1    = (unsigned short*)(ws + H1_OFF);
    unsigned short* hg    = (unsigned short*)(ws + HG_OFF);
    int*   tok_perm = (int*)(ws + PERM_OFF);
    float* probg    = (float*)(ws + PROBG_OFF);
    int*   idx      = (int*)(ws + IDX_OFF);
    float* prob     = (float*)(ws + PROB_OFF);
    int*   counts   = (int*)(ws + CNT_OFF);
    int*   offsets  = (int*)(ws + OFFS_OFF);
    int*   cursors  = (int*)(ws + CUR_OFF);
    int4*  tilemap  = (int4*)(ws + TILE_OFF);

    zero_counts<<<1, 64, 0, stream>>>(counts);

    quant_rows<1024><<<2048, 256, 0, stream>>>(sw1, sw1q);    // [2048,1024]
    quant_rows<2048><<<1024, 256, 0, stream>>>(sw2, sw2q);    // [1024,2048]
    quant_rows<1024><<<16384, 256, 0, stream>>>(ew1, ew1q);   // [8*2048,1024]
    quant_rows<2048><<<8192, 256, 0, stream>>>(ew2, ew2q);    // [8*1024,2048]

    ln_router<<<NTOK, 256, 0, stream>>>(x, gam, bet, rw, h, idx, prob, counts);

    // shared expert: h1 = silu(h @ sw1^T); out = h1 @ sw2^T
    gemm_nt<0><<<dim3(F_DIM / 128, NTOK / 128), 256, 0, stream>>>(
        h, sw1q, h1, F_DIM, D_MODEL, nullptr, 0, nullptr, nullptr);
    gemm_nt<1><<<dim3(D_MODEL / 128, NTOK / 128), 256, 0, stream>>>(
        h1, sw2q, out, D_MODEL, F_DIM, nullptr, 0, nullptr, nullptr);

    // routing bookkeeping
    scan_tiles<<<1, 64, 0, stream>>>(counts, offsets, cursors, tilemap);
    scatter_tokens<<<NTOK / 256, 256, 0, stream>>>(idx, prob, cursors, tok_perm, probg);
    gather_h<<<NTOK, 128, 0, stream>>>(h, tok_perm, hg);

    // routed experts (tile-mapped): h1 = silu(hg @ ew1[e]^T); out[tok] += p * (h1 @ ew2[e]^T)
    gemm_nt<2><<<dim3(F_DIM / 128, MAXT), 256, 0, stream>>>(
        hg, ew1q, h1, F_DIM, D_MODEL, tilemap, (long long)F_DIM * D_MODEL, nullptr, nullptr);
    gemm_nt<3><<<dim3(D_MODEL / 128, MAXT), 256, 0, stream>>>(
        h1, ew2q, out, D_MODEL, F_DIM, tilemap, (long long)D_MODEL * F_DIM, tok_perm, probg);
}